// Round 21
// baseline (1101.960 us; speedup 1.0000x reference)
//
#include <hip/hip_runtime.h>

#define NB 32
#define TT 12
#define NN 512
#define HH 64
#define EE 10
#define XS 80       // X row width (halves)
#define KD 240      // dense K = 3*80
#define RS (NB*NN)  // 16384 global rows
#define TTNN (TT*NN)
#define GP 164

typedef _Float16 f16;
typedef __attribute__((ext_vector_type(4))) _Float16 f16x4;
typedef __attribute__((ext_vector_type(8))) _Float16 f16x8;
typedef __attribute__((ext_vector_type(4))) float f32x4;

#define MFMA32(a,bb,c) __builtin_amdgcn_mfma_f32_16x16x32_f16(a,bb,c,0,0,0)
#define MFMA16(a,bb,c) __builtin_amdgcn_mfma_f32_16x16x16f16(a,bb,c,0,0,0)

__device__ __forceinline__ void barrier_lgkm() {
  asm volatile("s_waitcnt lgkmcnt(0)" ::: "memory");
  __builtin_amdgcn_s_barrier();
  __builtin_amdgcn_sched_barrier(0);
}

union SMem {
  f16 XtH[2][80][40];           // [buf][col][k]  12.8 KB
  f16 gH[64][GP];               // [row][g1|g2]   21 KB
};

// ---------------- fold Chebyshev into weights; transpose to [O][KD]; f16 --------
__global__ void fold_w_t(const float* __restrict__ src, f16* __restrict__ WtH,
                         int C, int O){
  int idx = blockIdx.x*256 + threadIdx.x;
  if (idx >= O*KD) return;
  int o = idx / KD;
  int k = idx % KD;
  int s = k / XS, c = k % XS;
  float v = 0.f;
  if (c < C) {
    if (s == 0)      v = src[c*O+o] - src[(2*C+c)*O+o];
    else if (s == 1) v = src[(C+c)*O+o];
    else             v = 2.f*src[(2*C+c)*O+o];
  }
  WtH[idx] = (f16)v;
}

// ---------------- A = softmax(relu(E E^T)): 8 rows/block, wave-per-row ----------
__global__ __launch_bounds__(512) void softmax_graph(
    const float* __restrict__ Emb, long long ebs,
    f16* __restrict__ AH, long long abs_)
{
  __shared__ float Es[NN*EE];
  int b  = blockIdx.x >> 6;
  int rt = blockIdx.x & 63;
  const float* Eb = Emb + (long long)b*ebs;
  int tid = threadIdx.x;
  for (int i = tid; i < NN*EE; i += 512) Es[i] = Eb[i];
  __syncthreads();
  int wave = tid >> 6, lane = tid & 63;
  int r = rt*8 + wave;
  float q[EE];
  #pragma unroll
  for (int e = 0; e < EE; ++e) q[e] = Es[r*EE + e];
  float sv[8];
  float mx = 0.f;
  #pragma unroll
  for (int j = 0; j < 8; ++j) {
    int m = 64*j + lane;
    float s = 0.f;
    #pragma unroll
    for (int e = 0; e < EE; ++e) s += q[e]*Es[m*EE + e];
    s = fmaxf(s, 0.f);
    sv[j] = s;
    mx = fmaxf(mx, s);
  }
  #pragma unroll
  for (int off = 32; off >= 1; off >>= 1) mx = fmaxf(mx, __shfl_xor(mx, off, 64));
  float sm = 0.f;
  #pragma unroll
  for (int j = 0; j < 8; ++j) { sv[j] = expf(sv[j] - mx); sm += sv[j]; }
  #pragma unroll
  for (int off = 32; off >= 1; off >>= 1) sm += __shfl_xor(sm, off, 64);
  float inv = 1.f / sm;
  #pragma unroll
  for (int j = 0; j < 8; ++j) {
    int m = 64*j + lane;
    AH[(long long)b*abs_ + (long long)r*NN + m] = (f16)(sv[j] * inv);
  }
}

// ---------------- B = A @ A, single-f16 ------------------------------------------
__global__ __launch_bounds__(256) void sq_mm(
    const f16* __restrict__ AH, long long astr,
    f16* __restrict__ BH, long long bstr)
{
  __shared__ f16 RsH[64][36], CsH[64][34];
  int b = blockIdx.z;
  int rows0 = blockIdx.y*64, cols0 = blockIdx.x*64;
  const f16* Ah = AH + (long long)b*astr;
  int tid = threadIdx.x, l = tid & 63, w = tid >> 6, lr = l & 15, lg = l >> 4;
  int ar = w*16 + lr;
  int st_row = tid >> 2, st_seg = tid & 3;
  int sx_m = tid >> 3, sx_sub = tid & 7;
  f32x4 acc[4] = {};
  for (int kt = 0; kt < 16; ++kt) {
    int k0 = kt*32;
    barrier_lgkm();
    {
      f16x8 vh = *(const f16x8*)&Ah[(long long)(rows0+st_row)*NN + k0 + 8*st_seg];
      *(f16x8*)&RsH[st_row][8*st_seg] = vh;
    }
    #pragma unroll
    for (int j = 0; j < 2; ++j) {
      int c4 = sx_sub + 8*j;   // 0..15
      f16x4 vh = *(const f16x4*)&Ah[(long long)(k0+sx_m)*NN + cols0 + 4*c4];
      #pragma unroll
      for (int q = 0; q < 4; ++q)
        CsH[4*c4+q][sx_m] = vh[q];
    }
    barrier_lgkm();
    f16x8 a_h = *(const f16x8*)&RsH[ar][8*lg];
    #pragma unroll
    for (int cf = 0; cf < 4; ++cf) {
      int c = cf*16 + lr;
      f16x8 b_h = *(const f16x8*)&CsH[c][8*lg];
      acc[cf] = MFMA32(a_h, b_h, acc[cf]);
    }
  }
  #pragma unroll
  for (int cf = 0; cf < 4; ++cf) {
    #pragma unroll
    for (int reg = 0; reg < 4; ++reg) {
      int r = rows0 + w*16 + lg*4 + reg;
      int c = cols0 + cf*16 + lr;
      BH[(long long)b*bstr + (long long)r*NN + c] = (f16)acc[cf][reg];
    }
  }
}

// ---------------- write one special column of X (dual layout, single f16) --------
__global__ void fill_col(f16* __restrict__ XRH, f16* __restrict__ XCH, int col,
                         const float* __restrict__ src, long long sstr){
  int row = blockIdx.x*256 + threadIdx.x;
  if (row >= RS) return;
  float v = src[(long long)(row>>9)*sstr + (row & 511)];
  f16 hi = (f16)v;
  XRH[(long long)row*XS + col] = hi;
  XCH[(long long)col*RS + row] = hi;
}

// ---------------- fused half-step: A fragments in registers, X-only LDS dbuf ----
template<int GATE, int DEC>
__global__ __launch_bounds__(512, 2) void fused_half(
    const f16* __restrict__ AH, const f16* __restrict__ A2H, long long astr,
    const f16* __restrict__ XiRH, const f16* __restrict__ XiCH,
    f16* __restrict__ XoRH, f16* __restrict__ XoCH,
    const f16* __restrict__ WH,
    const float* __restrict__ bias,
    float* __restrict__ hbuf, float* __restrict__ rb,
    const float* __restrict__ pWv, const float* __restrict__ pbv,
    float* __restrict__ outp, int t,
    const float* __restrict__ s0src, const float* __restrict__ s1src,
    int ns, int ns_next, int writeX)
{
  __shared__ SMem sm;
  __shared__ float gpart[64];
  const int b = blockIdx.x;
  const int rows0 = blockIdx.y * 64;
  const long long bNN = (long long)b*NN;
  const int tid = threadIdx.x;
  const int w = tid >> 6, l = tid & 63;
  const int lr = l & 15, lg = l >> 4;
  const int grp = w >> 2;
  const int w4 = w & 3;
  const int ar = w4*16 + lr;

  // A fragments register-resident: 16 kt x f16x8 = 64 VGPRs (own grp matrix only)
  f16x8 aF[16];
  {
    const f16* Ag = (grp ? A2H : AH) + (long long)b*astr
                  + (long long)(rows0 + ar)*NN + 8*lg;
    #pragma unroll
    for (int kt = 0; kt < 16; ++kt)
      aF[kt] = *(const f16x8*)&Ag[kt*32];
  }

  // X staging (col-major source): tid<320 covers 80 cols x 4 chunks of f16x8
  const int xc = tid >> 2;         // 0..127 (valid < 80)
  const int xo = tid & 3;
  const int xok = (xc < 80);
  const f16* XC1 = XiCH + (long long)(xok ? xc : 0)*RS + bNN;

  f16x8 xr0{}, xr1{};

  auto LOADX = [&](int kt, f16x8& x1){
    if (xok) x1 = *(const f16x8*)&XC1[kt*32 + 8*xo];
  };
  auto STOREX = [&](int buf, f16x8& x1){
    if (xok) *(f16x8*)&sm.XtH[buf][xc][8*xo] = x1;
  };
  f32x4 acc[5] = {};
  auto COMP = [&](int buf, f16x8 ah){
    __builtin_amdgcn_s_setprio(1);
    #pragma unroll
    for (int cf = 0; cf < 5; ++cf) {
      int c = cf*16 + lr;
      f16x8 bh = *(const f16x8*)&sm.XtH[buf][c][8*lg];
      acc[cf] = MFMA32(ah, bh, acc[cf]);
    }
    __builtin_amdgcn_s_setprio(0);
  };

  LOADX(0, xr0);
  LOADX(1, xr1);
  STOREX(0, xr0);
  barrier_lgkm();
  #pragma unroll
  for (int kt = 0; kt < 16; ++kt) {
    const int cur = kt & 1;
    if (kt+1 < 16) {
      if (cur == 0) STOREX(1, xr1); else STOREX(0, xr0);
    }
    if (kt+2 < 16) {
      if (cur == 0) LOADX(kt+2, xr0); else LOADX(kt+2, xr1);
    }
    COMP(cur, aF[kt]);
    barrier_lgkm();
  }

  // ---- dump g (single f16) into LDS union (Xt dead after final barrier) ----
  {
    int go_ = grp*80;
    #pragma unroll
    for (int cf = 0; cf < 5; ++cf) {
      int col = go_ + cf*16 + lr;
      #pragma unroll
      for (int reg = 0; reg < 4; ++reg) {
        int row = w4*16 + lg*4 + reg;
        sm.gH[row][col] = (f16)acc[cf][reg];
      }
    }
  }
  barrier_lgkm();

  // ---- dense: K = [x(rm global) | g1(LDS) | g2(LDS)], W single f16 ----
  constexpr int CFW = GATE ? 4 : 2;
  f32x4 accD[CFW] = {};
  const long long grow0 = bNN + rows0 + w4*16;
  const f16* xrH = XiRH + (grow0 + lr)*XS;
  #pragma unroll
  for (int c = 0; c < 15; ++c) {
    f16x4 a_h;
    if (c < 5) {
      a_h = *(const f16x4*)&xrH[c*16 + 4*lg];
    } else {
      a_h = *(const f16x4*)&sm.gH[w4*16 + lr][(c-5)*16 + 4*lg];
    }
    #pragma unroll
    for (int cf = 0; cf < CFW; ++cf) {
      int o = grp*(CFW*16) + cf*16 + lr;
      f16x4 b_h = *(const f16x4*)&WH[(long long)o*KD + c*16 + 4*lg];
      accD[cf] = MFMA16(a_h, b_h, accD[cf]);
    }
  }

  // ---- epilogue ----
  if constexpr (GATE) {
    #pragma unroll
    for (int cf = 0; cf < CFW; ++cf) {
      int o = grp*64 + cf*16 + lr;
      float bi = bias[o];
      #pragma unroll
      for (int reg = 0; reg < 4; ++reg) {
        long long grow = grow0 + lg*4 + reg;
        float v = 1.f/(1.f + expf(-(accD[cf][reg] + bi)));
        if (grp == 0) {
          float zh = v * hbuf[grow*HH + o];
          f16 hi = (f16)zh;
          XoRH[grow*XS + ns + o] = hi;
          XoCH[(long long)(ns+o)*RS + grow] = hi;
        } else {
          rb[grow*HH + (o - HH)] = v;
        }
      }
    }
    if (grp == 0 && lr < ns) {
      #pragma unroll
      for (int reg = 0; reg < 4; ++reg) {
        long long grow = grow0 + lg*4 + reg;
        f16 vh = XiRH[grow*XS + lr];
        XoRH[grow*XS + lr] = vh;
        XoCH[(long long)lr*RS + grow] = vh;
      }
    }
  } else {
    float gop[4] = {0.f,0.f,0.f,0.f};
    #pragma unroll
    for (int cf = 0; cf < CFW; ++cf) {
      int o = grp*32 + cf*16 + lr;
      float bi = bias[o];
      float pwv = 0.f;
      if constexpr (DEC) pwv = pWv[o];
      #pragma unroll
      for (int reg = 0; reg < 4; ++reg) {
        long long grow = grow0 + lg*4 + reg;
        float hc = tanhf(accD[cf][reg] + bi);
        float rv = rb[grow*HH + o];
        float hv = hbuf[grow*HH + o];
        float hn = rv*hv + (1.f - rv)*hc;
        hbuf[grow*HH + o] = hn;
        if (writeX) {
          f16 hi = (f16)hn;
          XoRH[grow*XS + ns_next + o] = hi;
          XoCH[(long long)(ns_next+o)*RS + grow] = hi;
        }
        if constexpr (DEC) gop[reg] += hn * pwv;
      }
    }
    if constexpr (DEC) {
      #pragma unroll
      for (int reg = 0; reg < 4; ++reg) {
        #pragma unroll
        for (int off = 8; off >= 1; off >>= 1)
          gop[reg] += __shfl_xor(gop[reg], off, 64);
      }
      if (grp == 1 && lr == 0) {
        #pragma unroll
        for (int reg = 0; reg < 4; ++reg)
          gpart[w4*16 + lg*4 + reg] = gop[reg];
      }
      barrier_lgkm();
      if (grp == 0 && lr == 0) {
        float pb0 = pbv[0];
        #pragma unroll
        for (int reg = 0; reg < 4; ++reg) {
          int n = rows0 + w4*16 + lg*4 + reg;
          long long grow = bNN + n;
          float go = gop[reg] + gpart[w4*16 + lg*4 + reg] + pb0;
          outp[((long long)b*TT + t)*NN + n] = go;
          if (writeX) {
            f16 hi = (f16)go;
            XoRH[grow*XS] = hi;
            XoCH[grow] = hi;
            float yv = s1src[(long long)b*TTNN + n];
            f16 hy = (f16)yv;
            XoRH[grow*XS + 1] = hy;
            XoCH[RS + grow] = hy;
          }
        }
      }
    } else {
      if (writeX && grp == 0 && lr == 0) {
        #pragma unroll
        for (int reg = 0; reg < 4; ++reg) {
          int n = rows0 + w4*16 + lg*4 + reg;
          long long grow = bNN + n;
          float v0 = s0src ? s0src[(long long)b*TTNN + n] : 0.f;
          f16 h0 = (f16)v0;
          XoRH[grow*XS] = h0;
          XoCH[grow] = h0;
          if (ns_next == 2 && s1src) {
            float v1 = s1src[(long long)b*TTNN + n];
            f16 h1 = (f16)v1;
            XoRH[grow*XS + 1] = h1;
            XoCH[RS + grow] = h1;
          }
        }
      }
    }
  }
}

// ---------------- E_dyn = ne + h @ hyper_W + hyper_b -----------------------------
__global__ __launch_bounds__(256) void edyn_k(
    const float* __restrict__ h, const float* __restrict__ ne,
    const float* __restrict__ hW, const float* __restrict__ hb, float* __restrict__ Ed)
{
  int row = blockIdx.x*4 + (threadIdx.x >> 6);
  int lane = threadIdx.x & 63;
  float hv = h[(long long)row*HH + lane];
  float myval = 0.f;
  #pragma unroll
  for (int e = 0; e < EE; ++e) {
    float v = hv * hW[lane*EE + e];
    #pragma unroll
    for (int off = 32; off >= 1; off >>= 1) v += __shfl_xor(v, off, 64);
    if (lane == e) myval = v;
  }
  if (lane < EE) {
    int n = row & 511;
    Ed[(long long)row*EE + lane] = ne[n*EE + lane] + hb[lane] + myval;
  }
}

extern "C" void kernel_launch(void* const* d_in, const int* in_sizes, int n_in,
                              void* d_out, int out_size, void* d_ws, size_t ws_size,
                              hipStream_t stream)
{
  const float* x    = (const float*)d_in[0];
  const float* ycov = (const float*)d_in[1];
  const float* ne   = (const float*)d_in[2];
  const float* egW  = (const float*)d_in[3];
  const float* egb  = (const float*)d_in[4];
  const float* euW  = (const float*)d_in[5];
  const float* eub  = (const float*)d_in[6];
  const float* dgW  = (const float*)d_in[7];
  const float* dgb  = (const float*)d_in[8];
  const float* duW  = (const float*)d_in[9];
  const float* dub  = (const float*)d_in[10];
  const float* pW   = (const float*)d_in[11];
  const float* pb   = (const float*)d_in[12];
  const float* hW   = (const float*)d_in[13];
  const float* hb   = (const float*)d_in[14];
  float* out = (float*)d_out;

  char* p = (char*)d_ws;
  f16* AsH  = (f16*)p; p += (size_t)NN*NN*2;
  f16* As2H = (f16*)p; p += (size_t)NN*NN*2;
  f16* AdH  = (f16*)p; p += (size_t)NB*NN*NN*2;
  f16* Ad2H = (f16*)p; p += (size_t)NB*NN*NN*2;
  f16* XaRH = (f16*)p; p += (size_t)RS*XS*2;
  f16* XaCH = (f16*)p; p += (size_t)RS*XS*2;
  f16* XbRH = (f16*)p; p += (size_t)RS*XS*2;
  f16* XbCH = (f16*)p; p += (size_t)RS*XS*2;
  float* h  = (float*)p; p += (size_t)RS*HH*4;
  float* rb = (float*)p; p += (size_t)RS*HH*4;
  float* Ed = (float*)p; p += (size_t)RS*EE*4;
  f16* WgeH = (f16*)p; p += (size_t)128*KD*2;
  f16* WueH = (f16*)p; p += (size_t)64*KD*2;
  f16* WgdH = (f16*)p; p += (size_t)128*KD*2;
  f16* WudH = (f16*)p; p += (size_t)64*KD*2;

  fold_w_t<<<(128*KD+255)/256, 256, 0, stream>>>(egW, WgeH, 65, 128);
  fold_w_t<<<(64*KD +255)/256, 256, 0, stream>>>(euW, WueH, 65, 64);
  fold_w_t<<<(128*KD+255)/256, 256, 0, stream>>>(dgW, WgdH, 66, 128);
  fold_w_t<<<(64*KD +255)/256, 256, 0, stream>>>(duW, WudH, 66, 64);

  softmax_graph<<<64, 512, 0, stream>>>(ne, 0, AsH, 0);
  sq_mm<<<dim3(8,8,1), 256, 0, stream>>>(AsH, 0, As2H, 0);
  (void)hipMemsetAsync(h, 0, (size_t)RS*HH*4, stream);
  (void)hipMemsetAsync(XaRH, 0, (size_t)RS*XS*2*4, stream);  // all 4 X arrays contiguous
  fill_col<<<(RS+255)/256, 256, 0, stream>>>(XaRH, XaCH, 0, x, (long long)TTNN);

  dim3 fgrid(NB, 8);
  for (int t = 0; t < TT; ++t) {
    fused_half<1,0><<<fgrid, 512, 0, stream>>>(
        AsH, As2H, 0,
        XaRH, XaCH, XbRH, XbCH,
        WgeH, egb, h, rb, nullptr, nullptr, nullptr, t,
        nullptr, nullptr, 1, 0, 1);
    fused_half<0,0><<<fgrid, 512, 0, stream>>>(
        AsH, As2H, 0,
        XbRH, XbCH, XaRH, XaCH,
        WueH, eub, h, rb, nullptr, nullptr, nullptr, t,
        (t < TT-1 ? x + (size_t)(t+1)*NN : nullptr),
        (t < TT-1 ? nullptr : ycov),
        1, (t < TT-1 ? 1 : 2), 1);
  }

  edyn_k<<<RS/4, 256, 0, stream>>>(h, ne, hW, hb, Ed);
  softmax_graph<<<NB*64, 512, 0, stream>>>(Ed, (long long)NN*EE, AdH, (long long)NN*NN);
  sq_mm<<<dim3(8,8,NB), 256, 0, stream>>>(AdH, (long long)NN*NN, Ad2H, (long long)NN*NN);

  for (int t = 0; t < TT; ++t) {
    fused_half<1,0><<<fgrid, 512, 0, stream>>>(
        AdH, Ad2H, (long long)NN*NN,
        XaRH, XaCH, XbRH, XbCH,
        WgdH, dgb, h, rb, nullptr, nullptr, nullptr, t,
        nullptr, nullptr, 2, 0, 1);
    fused_half<0,1><<<fgrid, 512, 0, stream>>>(
        AdH, Ad2H, (long long)NN*NN,
        XbRH, XbCH, XaRH, XaCH,
        WudH, dub, h, rb, pW, pb, out, t,
        nullptr, (t < TT-1 ? ycov + (size_t)(t+1)*NN : nullptr),
        2, 2, (t < TT-1 ? 1 : 0));
  }
}

// Round 22
// 1022.370 us; speedup vs baseline: 1.0778x; 1.0778x over previous
//
#include <hip/hip_runtime.h>

#define NB 32
#define TT 12
#define NN 512
#define HH 64
#define EE 10
#define XS 80       // X row width (halves)
#define KD 240      // dense K = 3*80
#define RS (NB*NN)  // 16384 global rows
#define TTNN (TT*NN)
#define GP 164

typedef _Float16 f16;
typedef __attribute__((ext_vector_type(4))) _Float16 f16x4;
typedef __attribute__((ext_vector_type(8))) _Float16 f16x8;
typedef __attribute__((ext_vector_type(4))) float f32x4;

#define MFMA32(a,bb,c) __builtin_amdgcn_mfma_f32_16x16x32_f16(a,bb,c,0,0,0)
#define MFMA16(a,bb,c) __builtin_amdgcn_mfma_f32_16x16x16f16(a,bb,c,0,0,0)

__device__ __forceinline__ void barrier_lgkm() {
  asm volatile("s_waitcnt lgkmcnt(0)" ::: "memory");
  __builtin_amdgcn_s_barrier();
  __builtin_amdgcn_sched_barrier(0);
}

union SMem {
  struct {
    f16 PsH[2][2][64][32];        // [buf][A=0/A2=1][row][k]  16 KB
    f16 XtH[2][80][40];           // [buf][col][k]            12.8 KB
  } s1;
  struct {
    f16 gH[64][GP];               // [row][g1|g2]             21 KB
  } s2;
};

// ---------------- fold Chebyshev into weights; transpose to [O][KD]; f16 --------
__global__ void fold_w_t(const float* __restrict__ src, f16* __restrict__ WtH,
                         int C, int O){
  int idx = blockIdx.x*256 + threadIdx.x;
  if (idx >= O*KD) return;
  int o = idx / KD;
  int k = idx % KD;
  int s = k / XS, c = k % XS;
  float v = 0.f;
  if (c < C) {
    if (s == 0)      v = src[c*O+o] - src[(2*C+c)*O+o];
    else if (s == 1) v = src[(C+c)*O+o];
    else             v = 2.f*src[(2*C+c)*O+o];
  }
  WtH[idx] = (f16)v;
}

// ---------------- A = softmax(relu(E E^T)): 8 rows/block, wave-per-row ----------
__global__ __launch_bounds__(512) void softmax_graph(
    const float* __restrict__ Emb, long long ebs,
    f16* __restrict__ AH, long long abs_)
{
  __shared__ float Es[NN*EE];
  int b  = blockIdx.x >> 6;
  int rt = blockIdx.x & 63;
  const float* Eb = Emb + (long long)b*ebs;
  int tid = threadIdx.x;
  for (int i = tid; i < NN*EE; i += 512) Es[i] = Eb[i];
  __syncthreads();
  int wave = tid >> 6, lane = tid & 63;
  int r = rt*8 + wave;
  float q[EE];
  #pragma unroll
  for (int e = 0; e < EE; ++e) q[e] = Es[r*EE + e];
  float sv[8];
  float mx = 0.f;
  #pragma unroll
  for (int j = 0; j < 8; ++j) {
    int m = 64*j + lane;
    float s = 0.f;
    #pragma unroll
    for (int e = 0; e < EE; ++e) s += q[e]*Es[m*EE + e];
    s = fmaxf(s, 0.f);
    sv[j] = s;
    mx = fmaxf(mx, s);
  }
  #pragma unroll
  for (int off = 32; off >= 1; off >>= 1) mx = fmaxf(mx, __shfl_xor(mx, off, 64));
  float sm = 0.f;
  #pragma unroll
  for (int j = 0; j < 8; ++j) { sv[j] = expf(sv[j] - mx); sm += sv[j]; }
  #pragma unroll
  for (int off = 32; off >= 1; off >>= 1) sm += __shfl_xor(sm, off, 64);
  float inv = 1.f / sm;
  #pragma unroll
  for (int j = 0; j < 8; ++j) {
    int m = 64*j + lane;
    AH[(long long)b*abs_ + (long long)r*NN + m] = (f16)(sv[j] * inv);
  }
}

// ---------------- B = A @ A, single-f16 ------------------------------------------
__global__ __launch_bounds__(256) void sq_mm(
    const f16* __restrict__ AH, long long astr,
    f16* __restrict__ BH, long long bstr)
{
  __shared__ f16 RsH[64][36], CsH[64][34];
  int b = blockIdx.z;
  int rows0 = blockIdx.y*64, cols0 = blockIdx.x*64;
  const f16* Ah = AH + (long long)b*astr;
  int tid = threadIdx.x, l = tid & 63, w = tid >> 6, lr = l & 15, lg = l >> 4;
  int ar = w*16 + lr;
  int st_row = tid >> 2, st_seg = tid & 3;
  int sx_m = tid >> 3, sx_sub = tid & 7;
  f32x4 acc[4] = {};
  for (int kt = 0; kt < 16; ++kt) {
    int k0 = kt*32;
    barrier_lgkm();
    {
      f16x8 vh = *(const f16x8*)&Ah[(long long)(rows0+st_row)*NN + k0 + 8*st_seg];
      *(f16x8*)&RsH[st_row][8*st_seg] = vh;
    }
    #pragma unroll
    for (int j = 0; j < 2; ++j) {
      int c4 = sx_sub + 8*j;   // 0..15
      f16x4 vh = *(const f16x4*)&Ah[(long long)(k0+sx_m)*NN + cols0 + 4*c4];
      #pragma unroll
      for (int q = 0; q < 4; ++q)
        CsH[4*c4+q][sx_m] = vh[q];
    }
    barrier_lgkm();
    f16x8 a_h = *(const f16x8*)&RsH[ar][8*lg];
    #pragma unroll
    for (int cf = 0; cf < 4; ++cf) {
      int c = cf*16 + lr;
      f16x8 b_h = *(const f16x8*)&CsH[c][8*lg];
      acc[cf] = MFMA32(a_h, b_h, acc[cf]);
    }
  }
  #pragma unroll
  for (int cf = 0; cf < 4; ++cf) {
    #pragma unroll
    for (int reg = 0; reg < 4; ++reg) {
      int r = rows0 + w*16 + lg*4 + reg;
      int c = cols0 + cf*16 + lr;
      BH[(long long)b*bstr + (long long)r*NN + c] = (f16)acc[cf][reg];
    }
  }
}

// ---------------- write one special column of X (dual layout, single f16) --------
__global__ void fill_col(f16* __restrict__ XRH, f16* __restrict__ XCH, int col,
                         const float* __restrict__ src, long long sstr){
  int row = blockIdx.x*256 + threadIdx.x;
  if (row >= RS) return;
  float v = src[(long long)(row>>9)*sstr + (row & 511)];
  f16 hi = (f16)v;
  XRH[(long long)row*XS + col] = hi;
  XCH[(long long)col*RS + row] = hi;
}

// ---------------- fused half-step: single-f16 everywhere -------------------------
template<int GATE, int DEC>
__global__ __launch_bounds__(512, 2) void fused_half(
    const f16* __restrict__ AH, const f16* __restrict__ A2H, long long astr,
    const f16* __restrict__ XiRH, const f16* __restrict__ XiCH,
    f16* __restrict__ XoRH, f16* __restrict__ XoCH,
    const f16* __restrict__ WH,
    const float* __restrict__ bias,
    float* __restrict__ hbuf, float* __restrict__ rb,
    const float* __restrict__ pWv, const float* __restrict__ pbv,
    float* __restrict__ outp, int t,
    const float* __restrict__ s0src, const float* __restrict__ s1src,
    int ns, int ns_next, int writeX)
{
  __shared__ SMem sm;
  __shared__ float gpart[64];
  const int b = blockIdx.x;
  const int rows0 = blockIdx.y * 64;
  const long long bNN = (long long)b*NN;
  const int tid = threadIdx.x;
  const int w = tid >> 6, l = tid & 63;
  const int lr = l & 15, lg = l >> 4;
  const int grp = w >> 2;
  const int w4 = w & 3;
  const int ar = w4*16 + lr;
  const int asw = (ar >> 2) & 3;

  // A/A2 staging mapping: tid<256 stages A-H, tid>=256 stages A2-H
  const int stw = (tid < 256) ? 0 : 1;
  const int at = tid & 255;
  const int st_row = at >> 2, st_seg = at & 3;
  const int a_sw = (st_row >> 2) & 3;
  const f16* PgH = (stw ? A2H : AH) + (long long)b*astr + (long long)rows0*NN;

  // X staging (col-major source, H only): tid<320 covers 80 cols x 4 chunks
  const int xc = tid >> 2;         // 0..127 (valid < 80)
  const int xo = tid & 3;
  const int xok = (xc < 80);
  const f16* XC1 = XiCH + (long long)(xok ? xc : 0)*RS + bNN;

  f16x8 rH0{}, x10{}, rH1{}, x11{};

  auto LOAD = [&](int kt, f16x8& rH, f16x8& x1){
    int k0 = kt*32;
    rH = *(const f16x8*)&PgH[(long long)st_row*NN + k0 + 8*st_seg];
    if (xok) x1 = *(const f16x8*)&XC1[k0 + 8*xo];
  };
  auto STORE = [&](int buf, f16x8& rH, f16x8& x1){
    *(f16x8*)&sm.s1.PsH[buf][stw][st_row][8*(st_seg ^ a_sw)] = rH;
    if (xok) *(f16x8*)&sm.s1.XtH[buf][xc][8*xo] = x1;
  };
  f32x4 acc[5] = {};
  auto COMP = [&](int buf){
    f16x8 ah = *(const f16x8*)&sm.s1.PsH[buf][grp][ar][8*(lg ^ asw)];
    __builtin_amdgcn_s_setprio(1);
    #pragma unroll
    for (int cf = 0; cf < 5; ++cf) {
      int c = cf*16 + lr;
      f16x8 bh = *(const f16x8*)&sm.s1.XtH[buf][c][8*lg];
      acc[cf] = MFMA32(ah, bh, acc[cf]);
    }
    __builtin_amdgcn_s_setprio(0);
  };

  LOAD(0, rH0,x10);
  LOAD(1, rH1,x11);
  STORE(0, rH0,x10);
  barrier_lgkm();
  #pragma unroll
  for (int kt2 = 0; kt2 < 8; ++kt2) {
    int kt = kt2*2;
    if (kt+2 < 16) LOAD(kt+2, rH0,x10);
    COMP(0);
    STORE(1, rH1,x11);
    barrier_lgkm();
    if (kt+3 < 16) LOAD(kt+3, rH1,x11);
    COMP(1);
    if (kt+2 < 16) STORE(0, rH0,x10);
    barrier_lgkm();
  }

  // ---- dump g (single f16) into LDS union ----
  {
    int go_ = grp*80;
    #pragma unroll
    for (int cf = 0; cf < 5; ++cf) {
      int col = go_ + cf*16 + lr;
      #pragma unroll
      for (int reg = 0; reg < 4; ++reg) {
        int row = w4*16 + lg*4 + reg;
        sm.s2.gH[row][col] = (f16)acc[cf][reg];
      }
    }
  }
  barrier_lgkm();

  // ---- dense: K = [x(rm global, H) | g1(LDS) | g2(LDS)], W single f16 ----
  constexpr int CFW = GATE ? 4 : 2;
  f32x4 accD[CFW] = {};
  const long long grow0 = bNN + rows0 + w4*16;
  const f16* xrH = XiRH + (grow0 + lr)*XS;
  #pragma unroll
  for (int c = 0; c < 15; ++c) {
    f16x4 a_h;
    if (c < 5) {
      a_h = *(const f16x4*)&xrH[c*16 + 4*lg];
    } else {
      a_h = *(const f16x4*)&sm.s2.gH[w4*16 + lr][(c-5)*16 + 4*lg];
    }
    #pragma unroll
    for (int cf = 0; cf < CFW; ++cf) {
      int o = grp*(CFW*16) + cf*16 + lr;
      f16x4 b_h = *(const f16x4*)&WH[(long long)o*KD + c*16 + 4*lg];
      accD[cf] = MFMA16(a_h, b_h, accD[cf]);
    }
  }

  // ---- epilogue ----
  if constexpr (GATE) {
    #pragma unroll
    for (int cf = 0; cf < CFW; ++cf) {
      int o = grp*64 + cf*16 + lr;
      float bi = bias[o];
      #pragma unroll
      for (int reg = 0; reg < 4; ++reg) {
        long long grow = grow0 + lg*4 + reg;
        float v = 1.f/(1.f + expf(-(accD[cf][reg] + bi)));
        if (grp == 0) {
          float zh = v * hbuf[grow*HH + o];
          f16 hi = (f16)zh;
          XoRH[grow*XS + ns + o] = hi;
          XoCH[(long long)(ns+o)*RS + grow] = hi;
        } else {
          rb[grow*HH + (o - HH)] = v;
        }
      }
    }
    if (grp == 0 && lr < ns) {
      #pragma unroll
      for (int reg = 0; reg < 4; ++reg) {
        long long grow = grow0 + lg*4 + reg;
        f16 vh = XiRH[grow*XS + lr];
        XoRH[grow*XS + lr] = vh;
        XoCH[(long long)lr*RS + grow] = vh;
      }
    }
  } else {
    float gop[4] = {0.f,0.f,0.f,0.f};
    #pragma unroll
    for (int cf = 0; cf < CFW; ++cf) {
      int o = grp*32 + cf*16 + lr;
      float bi = bias[o];
      float pwv = 0.f;
      if constexpr (DEC) pwv = pWv[o];
      #pragma unroll
      for (int reg = 0; reg < 4; ++reg) {
        long long grow = grow0 + lg*4 + reg;
        float hc = tanhf(accD[cf][reg] + bi);
        float rv = rb[grow*HH + o];
        float hv = hbuf[grow*HH + o];
        float hn = rv*hv + (1.f - rv)*hc;
        hbuf[grow*HH + o] = hn;
        if (writeX) {
          f16 hi = (f16)hn;
          XoRH[grow*XS + ns_next + o] = hi;
          XoCH[(long long)(ns_next+o)*RS + grow] = hi;
        }
        if constexpr (DEC) gop[reg] += hn * pwv;
      }
    }
    if constexpr (DEC) {
      #pragma unroll
      for (int reg = 0; reg < 4; ++reg) {
        #pragma unroll
        for (int off = 8; off >= 1; off >>= 1)
          gop[reg] += __shfl_xor(gop[reg], off, 64);
      }
      if (grp == 1 && lr == 0) {
        #pragma unroll
        for (int reg = 0; reg < 4; ++reg)
          gpart[w4*16 + lg*4 + reg] = gop[reg];
      }
      barrier_lgkm();
      if (grp == 0 && lr == 0) {
        float pb0 = pbv[0];
        #pragma unroll
        for (int reg = 0; reg < 4; ++reg) {
          int n = rows0 + w4*16 + lg*4 + reg;
          long long grow = bNN + n;
          float go = gop[reg] + gpart[w4*16 + lg*4 + reg] + pb0;
          outp[((long long)b*TT + t)*NN + n] = go;
          if (writeX) {
            f16 hi = (f16)go;
            XoRH[grow*XS] = hi;
            XoCH[grow] = hi;
            float yv = s1src[(long long)b*TTNN + n];
            f16 hy = (f16)yv;
            XoRH[grow*XS + 1] = hy;
            XoCH[RS + grow] = hy;
          }
        }
      }
    } else {
      if (writeX && grp == 0 && lr == 0) {
        #pragma unroll
        for (int reg = 0; reg < 4; ++reg) {
          int n = rows0 + w4*16 + lg*4 + reg;
          long long grow = bNN + n;
          float v0 = s0src ? s0src[(long long)b*TTNN + n] : 0.f;
          f16 h0 = (f16)v0;
          XoRH[grow*XS] = h0;
          XoCH[grow] = h0;
          if (ns_next == 2 && s1src) {
            float v1 = s1src[(long long)b*TTNN + n];
            f16 h1 = (f16)v1;
            XoRH[grow*XS + 1] = h1;
            XoCH[RS + grow] = h1;
          }
        }
      }
    }
  }
}

// ---------------- E_dyn = ne + h @ hyper_W + hyper_b -----------------------------
__global__ __launch_bounds__(256) void edyn_k(
    const float* __restrict__ h, const float* __restrict__ ne,
    const float* __restrict__ hW, const float* __restrict__ hb, float* __restrict__ Ed)
{
  int row = blockIdx.x*4 + (threadIdx.x >> 6);
  int lane = threadIdx.x & 63;
  float hv = h[(long long)row*HH + lane];
  float myval = 0.f;
  #pragma unroll
  for (int e = 0; e < EE; ++e) {
    float v = hv * hW[lane*EE + e];
    #pragma unroll
    for (int off = 32; off >= 1; off >>= 1) v += __shfl_xor(v, off, 64);
    if (lane == e) myval = v;
  }
  if (lane < EE) {
    int n = row & 511;
    Ed[(long long)row*EE + lane] = ne[n*EE + lane] + hb[lane] + myval;
  }
}

extern "C" void kernel_launch(void* const* d_in, const int* in_sizes, int n_in,
                              void* d_out, int out_size, void* d_ws, size_t ws_size,
                              hipStream_t stream)
{
  const float* x    = (const float*)d_in[0];
  const float* ycov = (const float*)d_in[1];
  const float* ne   = (const float*)d_in[2];
  const float* egW  = (const float*)d_in[3];
  const float* egb  = (const float*)d_in[4];
  const float* euW  = (const float*)d_in[5];
  const float* eub  = (const float*)d_in[6];
  const float* dgW  = (const float*)d_in[7];
  const float* dgb  = (const float*)d_in[8];
  const float* duW  = (const float*)d_in[9];
  const float* dub  = (const float*)d_in[10];
  const float* pW   = (const float*)d_in[11];
  const float* pb   = (const float*)d_in[12];
  const float* hW   = (const float*)d_in[13];
  const float* hb   = (const float*)d_in[14];
  float* out = (float*)d_out;

  char* p = (char*)d_ws;
  f16* AsH  = (f16*)p; p += (size_t)NN*NN*2;
  f16* As2H = (f16*)p; p += (size_t)NN*NN*2;
  f16* AdH  = (f16*)p; p += (size_t)NB*NN*NN*2;
  f16* Ad2H = (f16*)p; p += (size_t)NB*NN*NN*2;
  f16* XaRH = (f16*)p; p += (size_t)RS*XS*2;
  f16* XaCH = (f16*)p; p += (size_t)RS*XS*2;
  f16* XbRH = (f16*)p; p += (size_t)RS*XS*2;
  f16* XbCH = (f16*)p; p += (size_t)RS*XS*2;
  float* h  = (float*)p; p += (size_t)RS*HH*4;
  float* rb = (float*)p; p += (size_t)RS*HH*4;
  float* Ed = (float*)p; p += (size_t)RS*EE*4;
  f16* WgeH = (f16*)p; p += (size_t)128*KD*2;
  f16* WueH = (f16*)p; p += (size_t)64*KD*2;
  f16* WgdH = (f16*)p; p += (size_t)128*KD*2;
  f16* WudH = (f16*)p; p += (size_t)64*KD*2;

  fold_w_t<<<(128*KD+255)/256, 256, 0, stream>>>(egW, WgeH, 65, 128);
  fold_w_t<<<(64*KD +255)/256, 256, 0, stream>>>(euW, WueH, 65, 64);
  fold_w_t<<<(128*KD+255)/256, 256, 0, stream>>>(dgW, WgdH, 66, 128);
  fold_w_t<<<(64*KD +255)/256, 256, 0, stream>>>(duW, WudH, 66, 64);

  softmax_graph<<<64, 512, 0, stream>>>(ne, 0, AsH, 0);
  sq_mm<<<dim3(8,8,1), 256, 0, stream>>>(AsH, 0, As2H, 0);
  (void)hipMemsetAsync(h, 0, (size_t)RS*HH*4, stream);
  (void)hipMemsetAsync(XaRH, 0, (size_t)RS*XS*2*4, stream);  // all 4 X arrays contiguous
  fill_col<<<(RS+255)/256, 256, 0, stream>>>(XaRH, XaCH, 0, x, (long long)TTNN);

  dim3 fgrid(NB, 8);
  for (int t = 0; t < TT; ++t) {
    fused_half<1,0><<<fgrid, 512, 0, stream>>>(
        AsH, As2H, 0,
        XaRH, XaCH, XbRH, XbCH,
        WgeH, egb, h, rb, nullptr, nullptr, nullptr, t,
        nullptr, nullptr, 1, 0, 1);
    fused_half<0,0><<<fgrid, 512, 0, stream>>>(
        AsH, As2H, 0,
        XbRH, XbCH, XaRH, XaCH,
        WueH, eub, h, rb, nullptr, nullptr, nullptr, t,
        (t < TT-1 ? x + (size_t)(t+1)*NN : nullptr),
        (t < TT-1 ? nullptr : ycov),
        1, (t < TT-1 ? 1 : 2), 1);
  }

  edyn_k<<<RS/4, 256, 0, stream>>>(h, ne, hW, hb, Ed);
  softmax_graph<<<NB*64, 512, 0, stream>>>(Ed, (long long)NN*EE, AdH, (long long)NN*NN);
  sq_mm<<<dim3(8,8,NB), 256, 0, stream>>>(AdH, (long long)NN*NN, Ad2H, (long long)NN*NN);

  for (int t = 0; t < TT; ++t) {
    fused_half<1,0><<<fgrid, 512, 0, stream>>>(
        AdH, Ad2H, (long long)NN*NN,
        XaRH, XaCH, XbRH, XbCH,
        WgdH, dgb, h, rb, nullptr, nullptr, nullptr, t,
        nullptr, nullptr, 2, 0, 1);
    fused_half<0,1><<<fgrid, 512, 0, stream>>>(
        AdH, Ad2H, (long long)NN*NN,
        XbRH, XbCH, XaRH, XaCH,
        WudH, dub, h, rb, pW, pb, out, t,
        nullptr, (t < TT-1 ? ycov + (size_t)(t+1)*NN : nullptr),
        2, 2, (t < TT-1 ? 1 : 0));
  }
}